// Round 1
// baseline (27793.149 us; speedup 1.0000x reference)
//
#include <hip/hip_runtime.h>
#include <math.h>

// ---------------- problem constants ----------------
#define BATCH 256
#define TLEN  519          // W + MAXLAG
#define WIN   512
#define HID   256
#define PRED  24
#define NS    100
#define NLAG  7
#define GROWS (BATCH * NS) // 25600 decoder rows

// ---------------- workspace layout (float offsets) ----------------
#define OFF_SCALED 0
#define OFF_LOC    (OFF_SCALED + BATCH * TLEN)   // 132864
#define OFF_SCALE  (OFF_LOC + BATCH)
#define OFF_WIH0   (OFF_SCALE + BATCH)           // 133376  [f][j][q] f<7
#define OFF_WHH0   (OFF_WIH0 + NLAG * 1024)      // 140544  [k][j][q] k<256
#define OFF_WCAT1  (OFF_WHH0 + 256 * 1024)       // 402688  [k][j][q] k<512 (ih1|hh1)
#define OFF_B0     (OFF_WCAT1 + 512 * 1024)      // 926976  [j][q] combined b_ih0+b_hh0
#define OFF_B1     (OFF_B0 + 1024)
#define OFF_EH0    (OFF_B1 + 1024)               // 929024  encoder final states [b][j]
#define OFF_EC0    (OFF_EH0 + BATCH * HID)
#define OFF_EH1    (OFF_EC0 + BATCH * HID)
#define OFF_EC1    (OFF_EH1 + BATCH * HID)
#define OFF_ACC    (OFF_EC1 + BATCH * HID)       // 1191168 sample accumulators [b][p]
#define WS_FLOATS  (OFF_ACC + BATCH * PRED)      // 1197312 floats = 4.79 MB

// ---------------- helpers ----------------
__device__ __forceinline__ float sigm(float x) { return 1.0f / (1.0f + __expf(-x)); }
// tanh via exp; saturates correctly at +/-inf exp
__device__ __forceinline__ float ftanh(float x) {
    float e = __expf(2.0f * x);
    return 1.0f - 2.0f / (e + 1.0f);
}
__device__ __forceinline__ float softplus(float x) {
    return (x > 15.0f) ? x : log1pf(__expf(x));
}
__device__ __forceinline__ void fma4(float4& a, const float4 w, const float x) {
    a.x = fmaf(w.x, x, a.x);
    a.y = fmaf(w.y, x, a.y);
    a.z = fmaf(w.z, x, a.z);
    a.w = fmaf(w.w, x, a.w);
}

// ---------------- kernel 1: repack weights ----------------
// Layout: [k][j][q] so thread j does one coalesced float4 load per k and gets
// all 4 gates (i,f,g,o) of its hidden unit j. q: 0=i 1=f 2=g 3=o (gate row q*256+j).
__global__ __launch_bounds__(256) void prep_weights(
    const float* __restrict__ w_ih0, const float* __restrict__ w_hh0,
    const float* __restrict__ b_ih0, const float* __restrict__ b_hh0,
    const float* __restrict__ w_ih1, const float* __restrict__ w_hh1,
    const float* __restrict__ b_ih1, const float* __restrict__ b_hh1,
    float* __restrict__ ws) {
    int id = blockIdx.x * blockDim.x + threadIdx.x;   // grid covers 524288
    int g4 = id & 1023;
    int j = g4 >> 2, q = g4 & 3;
    int grow = q * HID + j;
    // wcat1: k<256 -> w_ih1 (input = h0), k>=256 -> w_hh1
    {
        int k = id >> 10;  // 0..511
        float v = (k < 256) ? w_ih1[grow * HID + k] : w_hh1[grow * HID + (k - 256)];
        ws[OFF_WCAT1 + id] = v;
    }
    if (id < 256 * 1024) {
        int k = id >> 10;
        ws[OFF_WHH0 + id] = w_hh0[grow * HID + k];
    }
    if (id < NLAG * 1024) {
        int f = id >> 10;
        ws[OFF_WIH0 + id] = w_ih0[grow * NLAG + f];
    }
    if (id < 1024) {
        ws[OFF_B0 + id] = b_ih0[grow] + b_hh0[grow];
        ws[OFF_B1 + id] = b_ih1[grow] + b_hh1[grow];
    }
}

// ---------------- kernel 2: normalize + zero accumulators ----------------
__global__ __launch_bounds__(256) void prep_norm(const float* __restrict__ x,
                                                 float* __restrict__ ws) {
    const int b = blockIdx.x, j = threadIdx.x;
    const float* row = x + b * TLEN;
    float s = 0.0f, s2 = 0.0f;
    for (int t = j; t < WIN; t += 256) {
        float v = row[NLAG + t];   // window = last 512 elements (indices 7..518)
        s += v;
        s2 = fmaf(v, v, s2);
    }
    // wave reduce
    #pragma unroll
    for (int off = 32; off > 0; off >>= 1) {
        s  += __shfl_down(s, off, 64);
        s2 += __shfl_down(s2, off, 64);
    }
    __shared__ float rs[4], rs2[4];
    __shared__ float sh_loc, sh_scale;
    int wave = j >> 6, lane = j & 63;
    if (lane == 0) { rs[wave] = s; rs2[wave] = s2; }
    __syncthreads();
    if (j == 0) {
        float S = rs[0] + rs[1] + rs[2] + rs[3];
        float S2 = rs2[0] + rs2[1] + rs2[2] + rs2[3];
        float mean = S * (1.0f / WIN);
        float var = S2 * (1.0f / WIN) - mean * mean;
        float sd = sqrtf(fmaxf(var, 0.0f));
        if (sd < 1e-10f) sd = 1.0f;
        sh_loc = mean; sh_scale = sd;
        ws[OFF_LOC + b] = mean;
        ws[OFF_SCALE + b] = sd;
    }
    __syncthreads();
    float loc = sh_loc, inv = 1.0f / sh_scale;
    for (int t = j; t < TLEN; t += 256) {
        ws[OFF_SCALED + b * TLEN + t] = (row[t] - loc) * inv;
    }
    if (j < PRED) ws[OFF_ACC + b * PRED + j] = 0.0f;   // ws is poisoned each launch
}

// ---------------- kernel 3: encoder (512 sequential steps) ----------------
// 128 blocks x 256 threads, 2 rows/block. Thread j owns hidden unit j of both
// rows; h vectors in LDS, c in registers. Weights streamed from L2 every step.
__global__ __launch_bounds__(256) void encoder_kernel(const float* __restrict__ wsr,
                                                      float* __restrict__ wsw) {
    const int j = threadIdx.x;
    const int bb = blockIdx.x;   // 0..127
    __shared__ float h0s[2][HID], h1s[2][HID], xs[2][NLAG];
    float c0[2] = {0.0f, 0.0f}, c1[2] = {0.0f, 0.0f};
    h0s[0][j] = 0.0f; h0s[1][j] = 0.0f;
    h1s[0][j] = 0.0f; h1s[1][j] = 0.0f;

    const float4* wih0v  = (const float4*)(wsr + OFF_WIH0);
    const float4* whh0v  = (const float4*)(wsr + OFF_WHH0);
    const float4* wcat1v = (const float4*)(wsr + OFF_WCAT1);
    const float4 bv0 = ((const float4*)(wsr + OFF_B0))[j];
    const float4 bv1 = ((const float4*)(wsr + OFF_B1))[j];
    const float* sc0 = wsr + OFF_SCALED + (bb * 2 + 0) * TLEN;
    const float* sc1 = wsr + OFF_SCALED + (bb * 2 + 1) * TLEN;

    for (int t = 0; t < WIN; ++t) {
        // stage the 7 lag values per row: x[f] = scaled[t + 6 - f]
        if (j < 2 * NLAG) {
            int r = j / NLAG, f = j % NLAG;
            xs[r][f] = (r ? sc1 : sc0)[t + 6 - f];
        }
        __syncthreads();
        // ---- layer 0 gates ----
        float4 a0 = bv0, a1 = bv0;
        #pragma unroll
        for (int f = 0; f < NLAG; ++f) {
            float4 w = wih0v[f * 256 + j];
            fma4(a0, w, xs[0][f]);
            fma4(a1, w, xs[1][f]);
        }
        for (int k = 0; k < HID; ++k) {
            float4 w = whh0v[k * 256 + j];
            fma4(a0, w, h0s[0][k]);
            fma4(a1, w, h0s[1][k]);
        }
        __syncthreads();   // everyone done reading old h0s
        c0[0] = sigm(a0.y) * c0[0] + sigm(a0.x) * ftanh(a0.z);
        c0[1] = sigm(a1.y) * c0[1] + sigm(a1.x) * ftanh(a1.z);
        h0s[0][j] = sigm(a0.w) * ftanh(c0[0]);
        h0s[1][j] = sigm(a1.w) * ftanh(c0[1]);
        __syncthreads();
        // ---- layer 1 gates ----
        float4 g0 = bv1, g1 = bv1;
        for (int k = 0; k < HID; ++k) {
            float4 w = wcat1v[k * 256 + j];
            fma4(g0, w, h0s[0][k]);
            fma4(g1, w, h0s[1][k]);
        }
        for (int k = 0; k < HID; ++k) {
            float4 w = wcat1v[(HID + k) * 256 + j];
            fma4(g0, w, h1s[0][k]);
            fma4(g1, w, h1s[1][k]);
        }
        __syncthreads();   // everyone done reading old h1s
        c1[0] = sigm(g0.y) * c1[0] + sigm(g0.x) * ftanh(g0.z);
        c1[1] = sigm(g1.y) * c1[1] + sigm(g1.x) * ftanh(g1.z);
        h1s[0][j] = sigm(g0.w) * ftanh(c1[0]);
        h1s[1][j] = sigm(g1.w) * ftanh(c1[1]);
        __syncthreads();
    }
    #pragma unroll
    for (int r = 0; r < 2; ++r) {
        int b = bb * 2 + r;
        wsw[OFF_EH0 + b * HID + j] = h0s[r][j];
        wsw[OFF_EC0 + b * HID + j] = c0[r];
        wsw[OFF_EH1 + b * HID + j] = h1s[r][j];
        wsw[OFF_EC1 + b * HID + j] = c1[r];
    }
}

// ---------------- kernel 4: decoder (24 sequential steps, 25600 rows) ----------------
#define RDEC 16
__global__ __launch_bounds__(256) void decoder_kernel(
    const float* __restrict__ wsr,
    const float* __restrict__ w_mu, const float* __restrict__ b_mu,
    const float* __restrict__ w_sigma, const float* __restrict__ b_sigma,
    const float* __restrict__ eps, float* __restrict__ wsw) {
    const int j = threadIdx.x;
    const int gr0 = blockIdx.x * RDEC;
    __shared__ float h0s[RDEC][HID], h1s[RDEC][HID];
    __shared__ float bufs[RDEC][NLAG];
    float c0[RDEC], c1[RDEC];

    const float4* wih0v  = (const float4*)(wsr + OFF_WIH0);
    const float4* whh0v  = (const float4*)(wsr + OFF_WHH0);
    const float4* wcat1v = (const float4*)(wsr + OFF_WCAT1);
    const float4 bv0 = ((const float4*)(wsr + OFF_B0))[j];
    const float4 bv1 = ((const float4*)(wsr + OFF_B1))[j];

    #pragma unroll
    for (int r = 0; r < RDEC; ++r) {
        int b = (gr0 + r) / NS;
        h0s[r][j] = wsr[OFF_EH0 + b * HID + j];
        h1s[r][j] = wsr[OFF_EH1 + b * HID + j];
        c0[r] = wsr[OFF_EC0 + b * HID + j];
        c1[r] = wsr[OFF_EC1 + b * HID + j];
    }
    if (j < RDEC * NLAG) {
        int r = j / NLAG, f = j % NLAG;
        int b = (gr0 + r) / NS;
        bufs[r][f] = wsr[OFF_SCALED + b * TLEN + WIN + f];   // last 7 scaled values
    }
    __syncthreads();

    float* acc = wsw + OFF_ACC;
    for (int p = 0; p < PRED; ++p) {
        // ---- layer 0 ----
        float4 a[RDEC];
        #pragma unroll
        for (int r = 0; r < RDEC; ++r) a[r] = bv0;
        #pragma unroll
        for (int f = 0; f < NLAG; ++f) {
            float4 w = wih0v[f * 256 + j];
            #pragma unroll
            for (int r = 0; r < RDEC; ++r) fma4(a[r], w, bufs[r][6 - f]);  // x = buf reversed
        }
        for (int k = 0; k < HID; ++k) {
            float4 w = whh0v[k * 256 + j];
            #pragma unroll
            for (int r = 0; r < RDEC; ++r) fma4(a[r], w, h0s[r][k]);
        }
        __syncthreads();
        #pragma unroll
        for (int r = 0; r < RDEC; ++r) {
            c0[r] = sigm(a[r].y) * c0[r] + sigm(a[r].x) * ftanh(a[r].z);
            h0s[r][j] = sigm(a[r].w) * ftanh(c0[r]);
        }
        __syncthreads();
        // ---- layer 1 ----
        #pragma unroll
        for (int r = 0; r < RDEC; ++r) a[r] = bv1;
        for (int k = 0; k < HID; ++k) {
            float4 w = wcat1v[k * 256 + j];
            #pragma unroll
            for (int r = 0; r < RDEC; ++r) fma4(a[r], w, h0s[r][k]);
        }
        for (int k = 0; k < HID; ++k) {
            float4 w = wcat1v[(HID + k) * 256 + j];
            #pragma unroll
            for (int r = 0; r < RDEC; ++r) fma4(a[r], w, h1s[r][k]);
        }
        __syncthreads();
        #pragma unroll
        for (int r = 0; r < RDEC; ++r) {
            c1[r] = sigm(a[r].y) * c1[r] + sigm(a[r].x) * ftanh(a[r].z);
            h1s[r][j] = sigm(a[r].w) * ftanh(c1[r]);
        }
        __syncthreads();
        // ---- mu / sigma / sample: one wave handles rows wave, wave+4, ... ----
        int wave = j >> 6, lane = j & 63;
        for (int r = wave; r < RDEC; r += 4) {
            float sm = 0.0f, ss = 0.0f;
            #pragma unroll
            for (int q = 0; q < 4; ++q) {
                int k = lane + 64 * q;
                float hv = h1s[r][k];
                sm = fmaf(w_mu[k], hv, sm);
                ss = fmaf(w_sigma[k], hv, ss);
            }
            #pragma unroll
            for (int off = 32; off > 0; off >>= 1) {
                sm += __shfl_down(sm, off, 64);
                ss += __shfl_down(ss, off, 64);
            }
            if (lane == 0) {
                float mu = sm + b_mu[0];
                float sg = softplus(ss + b_sigma[0]);
                int gr = gr0 + r;
                float smp = fmaf(sg, eps[p * GROWS + gr], mu);
                atomicAdd(&acc[(gr / NS) * PRED + p], smp);
                #pragma unroll
                for (int f = 0; f < NLAG - 1; ++f) bufs[r][f] = bufs[r][f + 1];
                bufs[r][NLAG - 1] = smp;
            }
        }
        __syncthreads();
    }
}

// ---------------- kernel 5: finalize ----------------
__global__ __launch_bounds__(256) void finalize_kernel(const float* __restrict__ ws,
                                                       float* __restrict__ out) {
    int i = blockIdx.x * blockDim.x + threadIdx.x;
    if (i < BATCH * PRED) {
        int b = i / PRED;
        out[i] = ws[OFF_ACC + i] * (1.0f / NS) * ws[OFF_SCALE + b] + ws[OFF_LOC + b];
    }
}

// ---------------- launch ----------------
extern "C" void kernel_launch(void* const* d_in, const int* in_sizes, int n_in,
                              void* d_out, int out_size, void* d_ws, size_t ws_size,
                              hipStream_t stream) {
    const float* targets = (const float*)d_in[0];
    const float* w_ih0 = (const float*)d_in[1];
    const float* w_hh0 = (const float*)d_in[2];
    const float* b_ih0 = (const float*)d_in[3];
    const float* b_hh0 = (const float*)d_in[4];
    const float* w_ih1 = (const float*)d_in[5];
    const float* w_hh1 = (const float*)d_in[6];
    const float* b_ih1 = (const float*)d_in[7];
    const float* b_hh1 = (const float*)d_in[8];
    const float* w_mu = (const float*)d_in[9];
    const float* b_mu = (const float*)d_in[10];
    const float* w_sigma = (const float*)d_in[11];
    const float* b_sigma = (const float*)d_in[12];
    const float* eps = (const float*)d_in[13];
    float* ws = (float*)d_ws;
    float* out = (float*)d_out;

    hipLaunchKernelGGL(prep_weights, dim3(2048), dim3(256), 0, stream,
                       w_ih0, w_hh0, b_ih0, b_hh0, w_ih1, w_hh1, b_ih1, b_hh1, ws);
    hipLaunchKernelGGL(prep_norm, dim3(BATCH), dim3(256), 0, stream, targets, ws);
    hipLaunchKernelGGL(encoder_kernel, dim3(BATCH / 2), dim3(256), 0, stream, ws, ws);
    hipLaunchKernelGGL(decoder_kernel, dim3(GROWS / RDEC), dim3(256), 0, stream,
                       ws, w_mu, b_mu, w_sigma, b_sigma, eps, ws);
    hipLaunchKernelGGL(finalize_kernel, dim3((BATCH * PRED + 255) / 256), dim3(256), 0,
                       stream, ws, out);
}

// Round 2
// 20000.677 us; speedup vs baseline: 1.3896x; 1.3896x over previous
//
#include <hip/hip_runtime.h>
#include <math.h>

// ---------------- problem constants ----------------
#define BATCH 256
#define TLEN  519          // W + MAXLAG
#define WIN   512
#define HID   256
#define PRED  24
#define NS    100
#define NLAG  7
#define GROWS (BATCH * NS) // 25600 decoder rows

// ---------------- workspace layout (float/uint offsets) ----------------
#define OFF_SCALED 0
#define OFF_LOC    (OFF_SCALED + BATCH * TLEN)   // 132864
#define OFF_SCALE  (OFF_LOC + BATCH)
#define OFF_WIH0   (OFF_SCALE + BATCH)           // 133376  fp32 [f][j][q], f<7
#define OFF_WHH0H  (OFF_WIH0 + NLAG * 1024)      // 140544  half2 [p][j][q], p<128 (k pairs)
#define OFF_WCAT1H (OFF_WHH0H + 128 * 1024)      // 271616  half2 [p][j][q], p<256 (ih1|hh1)
#define OFF_B0     (OFF_WCAT1H + 256 * 1024)     // 533760  fp32 combined b_ih0+b_hh0
#define OFF_B1     (OFF_B0 + 1024)
#define OFF_EH0    (OFF_B1 + 1024)               // encoder final states fp32 [b][j]
#define OFF_EC0    (OFF_EH0 + BATCH * HID)
#define OFF_EH1    (OFF_EC0 + BATCH * HID)
#define OFF_EC1    (OFF_EH1 + BATCH * HID)
#define OFF_ACC    (OFF_EC1 + BATCH * HID)       // sample accumulators [b][p]
#define WS_FLOATS  (OFF_ACC + BATCH * PRED)      // 804096 floats = 3.2 MB

// ---------------- helpers ----------------
typedef _Float16 h2_t __attribute__((ext_vector_type(2)));

__device__ __forceinline__ float sigm(float x) { return 1.0f / (1.0f + __expf(-x)); }
__device__ __forceinline__ float ftanh(float x) {
    float e = __expf(2.0f * x);
    return 1.0f - 2.0f / (e + 1.0f);
}
__device__ __forceinline__ float softplus(float x) {
    return (x > 15.0f) ? x : log1pf(__expf(x));
}
__device__ __forceinline__ void fma4(float4& a, const float4 w, const float x) {
    a.x = fmaf(w.x, x, a.x);
    a.y = fmaf(w.y, x, a.y);
    a.z = fmaf(w.z, x, a.z);
    a.w = fmaf(w.w, x, a.w);
}
// fp32 += half2 . half2  (v_dot2_f32_f16)
__device__ __forceinline__ float dot2(uint h, uint w, float acc) {
    return __builtin_amdgcn_fdot2(__builtin_bit_cast(h2_t, h),
                                  __builtin_bit_cast(h2_t, w), acc, false);
}
__device__ __forceinline__ void dot2x4(float4& a, const uint h, const uint4 w) {
    a.x = dot2(h, w.x, a.x);
    a.y = dot2(h, w.y, a.y);
    a.z = dot2(h, w.z, a.z);
    a.w = dot2(h, w.w, a.w);
}
__device__ __forceinline__ uint packh2(float a, float b) {
    h2_t h;
    h.x = (_Float16)a;
    h.y = (_Float16)b;
    return __builtin_bit_cast(uint, h);
}

// ---------------- kernel 1: repack weights ----------------
// half2 layout [p][j][q]: thread j loads uint4 -> all 4 gates (i,f,g,o) of unit j
// for k-pair p. Gate row = q*256+j.
__global__ __launch_bounds__(256) void prep_weights(
    const float* __restrict__ w_ih0, const float* __restrict__ w_hh0,
    const float* __restrict__ b_ih0, const float* __restrict__ b_hh0,
    const float* __restrict__ w_ih1, const float* __restrict__ w_hh1,
    const float* __restrict__ b_ih1, const float* __restrict__ b_hh1,
    float* __restrict__ ws) {
    int id = blockIdx.x * blockDim.x + threadIdx.x;   // grid covers 262144
    int g4 = id & 1023;
    int j = g4 >> 2, q = g4 & 3;
    int grow = q * HID + j;
    uint* wsu = (uint*)ws;
    // wcat1 half2: p<128 -> w_ih1 (input = h0), p>=128 -> w_hh1 (input = h1)
    {
        int p = id >> 10;  // 0..255
        int k0 = 2 * p;
        float v0, v1;
        if (k0 < 256) { v0 = w_ih1[grow * HID + k0];       v1 = w_ih1[grow * HID + k0 + 1]; }
        else          { v0 = w_hh1[grow * HID + k0 - 256]; v1 = w_hh1[grow * HID + k0 - 255]; }
        wsu[OFF_WCAT1H + id] = packh2(v0, v1);
    }
    if (id < 128 * 1024) {
        int p = id >> 10;
        wsu[OFF_WHH0H + id] = packh2(w_hh0[grow * HID + 2 * p], w_hh0[grow * HID + 2 * p + 1]);
    }
    if (id < NLAG * 1024) {
        int f = id >> 10;
        ws[OFF_WIH0 + id] = w_ih0[grow * NLAG + f];
    }
    if (id < 1024) {
        ws[OFF_B0 + id] = b_ih0[grow] + b_hh0[grow];
        ws[OFF_B1 + id] = b_ih1[grow] + b_hh1[grow];
    }
}

// ---------------- kernel 2: normalize + zero accumulators ----------------
__global__ __launch_bounds__(256) void prep_norm(const float* __restrict__ x,
                                                 float* __restrict__ ws) {
    const int b = blockIdx.x, j = threadIdx.x;
    const float* row = x + b * TLEN;
    float s = 0.0f, s2 = 0.0f;
    for (int t = j; t < WIN; t += 256) {
        float v = row[NLAG + t];
        s += v;
        s2 = fmaf(v, v, s2);
    }
    #pragma unroll
    for (int off = 32; off > 0; off >>= 1) {
        s  += __shfl_down(s, off, 64);
        s2 += __shfl_down(s2, off, 64);
    }
    __shared__ float rs[4], rs2[4];
    __shared__ float sh_loc, sh_scale;
    int wave = j >> 6, lane = j & 63;
    if (lane == 0) { rs[wave] = s; rs2[wave] = s2; }
    __syncthreads();
    if (j == 0) {
        float S = rs[0] + rs[1] + rs[2] + rs[3];
        float S2 = rs2[0] + rs2[1] + rs2[2] + rs2[3];
        float mean = S * (1.0f / WIN);
        float var = S2 * (1.0f / WIN) - mean * mean;
        float sd = sqrtf(fmaxf(var, 0.0f));
        if (sd < 1e-10f) sd = 1.0f;
        sh_loc = mean; sh_scale = sd;
        ws[OFF_LOC + b] = mean;
        ws[OFF_SCALE + b] = sd;
    }
    __syncthreads();
    float loc = sh_loc, inv = 1.0f / sh_scale;
    for (int t = j; t < TLEN; t += 256) {
        ws[OFF_SCALED + b * TLEN + t] = (row[t] - loc) * inv;
    }
    if (j < PRED) ws[OFF_ACC + b * PRED + j] = 0.0f;
}

// ---------------- kernel 3: encoder (512 sequential steps) ----------------
// 128 blocks x 256 threads, 2 rows/block. Per-CU-L2-BW-bound: 1.59 MB fp16
// weights streamed per step per block. h states fp16 in LDS (half2-packed),
// c states fp32 in registers, gate accumulation fp32 via v_dot2_f32_f16.
__global__ __launch_bounds__(256) void encoder_kernel(const float* __restrict__ wsr,
                                                      float* __restrict__ wsw) {
    const int j = threadIdx.x;
    const int bb = blockIdx.x;   // 0..127
    __shared__ uint h0p[2][128], h1p[2][128];   // half2-packed h, [row][pair]
    __shared__ float xs[2][NLAG];
    float c0[2] = {0.0f, 0.0f}, c1[2] = {0.0f, 0.0f};
    if (j < 128) { h0p[0][j] = 0; h0p[1][j] = 0; h1p[0][j] = 0; h1p[1][j] = 0; }

    const float4* wih0v = (const float4*)(wsr + OFF_WIH0);
    const uint4* whh0q  = (const uint4*)((const uint*)wsr + OFF_WHH0H);
    const uint4* wcat1q = (const uint4*)((const uint*)wsr + OFF_WCAT1H);
    const float4 bv0 = ((const float4*)(wsr + OFF_B0))[j];
    const float4 bv1 = ((const float4*)(wsr + OFF_B1))[j];
    const float* sc0 = wsr + OFF_SCALED + (bb * 2 + 0) * TLEN;
    const float* sc1 = wsr + OFF_SCALED + (bb * 2 + 1) * TLEN;

    for (int t = 0; t < WIN; ++t) {
        if (j < 2 * NLAG) {
            int r = j / NLAG, f = j % NLAG;
            xs[r][f] = (r ? sc1 : sc0)[t + 6 - f];
        }
        __syncthreads();
        // ---- layer 0 gates ----
        float4 a0 = bv0, a1 = bv0;
        #pragma unroll
        for (int f = 0; f < NLAG; ++f) {
            float4 w = wih0v[f * 256 + j];
            fma4(a0, w, xs[0][f]);
            fma4(a1, w, xs[1][f]);
        }
        #pragma unroll 4
        for (int p = 0; p < 128; ++p) {
            uint4 w = whh0q[p * 256 + j];
            uint ha = h0p[0][p], hb = h0p[1][p];
            dot2x4(a0, ha, w);
            dot2x4(a1, hb, w);
        }
        __syncthreads();
        c0[0] = sigm(a0.y) * c0[0] + sigm(a0.x) * ftanh(a0.z);
        c0[1] = sigm(a1.y) * c0[1] + sigm(a1.x) * ftanh(a1.z);
        ((_Float16*)h0p)[0 * 256 + j] = (_Float16)(sigm(a0.w) * ftanh(c0[0]));
        ((_Float16*)h0p)[1 * 256 + j] = (_Float16)(sigm(a1.w) * ftanh(c0[1]));
        __syncthreads();
        // ---- layer 1 gates ----
        float4 g0 = bv1, g1 = bv1;
        #pragma unroll 4
        for (int p = 0; p < 128; ++p) {
            uint4 w = wcat1q[p * 256 + j];
            uint ha = h0p[0][p], hb = h0p[1][p];
            dot2x4(g0, ha, w);
            dot2x4(g1, hb, w);
        }
        #pragma unroll 4
        for (int p = 0; p < 128; ++p) {
            uint4 w = wcat1q[(128 + p) * 256 + j];
            uint ha = h1p[0][p], hb = h1p[1][p];
            dot2x4(g0, ha, w);
            dot2x4(g1, hb, w);
        }
        __syncthreads();
        c1[0] = sigm(g0.y) * c1[0] + sigm(g0.x) * ftanh(g0.z);
        c1[1] = sigm(g1.y) * c1[1] + sigm(g1.x) * ftanh(g1.z);
        ((_Float16*)h1p)[0 * 256 + j] = (_Float16)(sigm(g0.w) * ftanh(c1[0]));
        ((_Float16*)h1p)[1 * 256 + j] = (_Float16)(sigm(g1.w) * ftanh(c1[1]));
        __syncthreads();
    }
    #pragma unroll
    for (int r = 0; r < 2; ++r) {
        int b = bb * 2 + r;
        wsw[OFF_EH0 + b * HID + j] = (float)((_Float16*)h0p)[r * 256 + j];
        wsw[OFF_EC0 + b * HID + j] = c0[r];
        wsw[OFF_EH1 + b * HID + j] = (float)((_Float16*)h1p)[r * 256 + j];
        wsw[OFF_EC1 + b * HID + j] = c1[r];
    }
}

// ---------------- kernel 4: decoder (24 sequential steps, 25600 rows) ----------------
// h states half2-packed TRANSPOSED [pair][row] so the 16 rows' h2 for a fixed
// k-pair load as 4x ds_read_b128 (broadcast). Gate accum fp32 in a[16] regs.
#define RDEC 16
__global__ __launch_bounds__(256) void decoder_kernel(
    const float* __restrict__ wsr,
    const float* __restrict__ w_mu, const float* __restrict__ b_mu,
    const float* __restrict__ w_sigma, const float* __restrict__ b_sigma,
    const float* __restrict__ eps, float* __restrict__ wsw) {
    const int j = threadIdx.x;
    const int gr0 = blockIdx.x * RDEC;
    __shared__ uint h0t[128][RDEC], h1t[128][RDEC];   // half2-packed, [pair][row]
    __shared__ float bufs[RDEC][NLAG];
    float c0[RDEC], c1[RDEC];

    const float4* wih0v = (const float4*)(wsr + OFF_WIH0);
    const uint4* whh0q  = (const uint4*)((const uint*)wsr + OFF_WHH0H);
    const uint4* wcat1q = (const uint4*)((const uint*)wsr + OFF_WCAT1H);
    const float4 bv0 = ((const float4*)(wsr + OFF_B0))[j];
    const float4 bv1 = ((const float4*)(wsr + OFF_B1))[j];

    // init: convert encoder states to half, transposed layout.
    // halves index for (pair p=j>>1, row r, lo/hi j&1): p*32 + r*2 + (j&1)
    _Float16* h0h = (_Float16*)h0t;
    _Float16* h1h = (_Float16*)h1t;
    #pragma unroll
    for (int r = 0; r < RDEC; ++r) {
        int b = (gr0 + r) / NS;
        h0h[(j >> 1) * 32 + r * 2 + (j & 1)] = (_Float16)wsr[OFF_EH0 + b * HID + j];
        h1h[(j >> 1) * 32 + r * 2 + (j & 1)] = (_Float16)wsr[OFF_EH1 + b * HID + j];
        c0[r] = wsr[OFF_EC0 + b * HID + j];
        c1[r] = wsr[OFF_EC1 + b * HID + j];
    }
    if (j < RDEC * NLAG) {
        int r = j / NLAG, f = j % NLAG;
        int b = (gr0 + r) / NS;
        bufs[r][f] = wsr[OFF_SCALED + b * TLEN + WIN + f];
    }
    __syncthreads();

    float* acc = wsw + OFF_ACC;
    for (int st = 0; st < PRED; ++st) {
        // ---- layer 0 ----
        float4 a[RDEC];
        #pragma unroll
        for (int r = 0; r < RDEC; ++r) a[r] = bv0;
        #pragma unroll
        for (int f = 0; f < NLAG; ++f) {
            float4 w = wih0v[f * 256 + j];
            #pragma unroll
            for (int r = 0; r < RDEC; ++r) fma4(a[r], w, bufs[r][6 - f]);
        }
        #pragma unroll 2
        for (int p = 0; p < 128; ++p) {
            uint4 w = whh0q[p * 256 + j];
            const uint4* hp = (const uint4*)&h0t[p][0];
            uint hr[RDEC];
            *(uint4*)&hr[0]  = hp[0];
            *(uint4*)&hr[4]  = hp[1];
            *(uint4*)&hr[8]  = hp[2];
            *(uint4*)&hr[12] = hp[3];
            #pragma unroll
            for (int r = 0; r < RDEC; ++r) dot2x4(a[r], hr[r], w);
        }
        __syncthreads();
        #pragma unroll
        for (int r = 0; r < RDEC; ++r) {
            c0[r] = sigm(a[r].y) * c0[r] + sigm(a[r].x) * ftanh(a[r].z);
            h0h[(j >> 1) * 32 + r * 2 + (j & 1)] = (_Float16)(sigm(a[r].w) * ftanh(c0[r]));
        }
        __syncthreads();
        // ---- layer 1 ----
        #pragma unroll
        for (int r = 0; r < RDEC; ++r) a[r] = bv1;
        #pragma unroll 2
        for (int p = 0; p < 128; ++p) {
            uint4 w = wcat1q[p * 256 + j];
            const uint4* hp = (const uint4*)&h0t[p][0];
            uint hr[RDEC];
            *(uint4*)&hr[0]  = hp[0];
            *(uint4*)&hr[4]  = hp[1];
            *(uint4*)&hr[8]  = hp[2];
            *(uint4*)&hr[12] = hp[3];
            #pragma unroll
            for (int r = 0; r < RDEC; ++r) dot2x4(a[r], hr[r], w);
        }
        #pragma unroll 2
        for (int p = 0; p < 128; ++p) {
            uint4 w = wcat1q[(128 + p) * 256 + j];
            const uint4* hp = (const uint4*)&h1t[p][0];
            uint hr[RDEC];
            *(uint4*)&hr[0]  = hp[0];
            *(uint4*)&hr[4]  = hp[1];
            *(uint4*)&hr[8]  = hp[2];
            *(uint4*)&hr[12] = hp[3];
            #pragma unroll
            for (int r = 0; r < RDEC; ++r) dot2x4(a[r], hr[r], w);
        }
        __syncthreads();
        #pragma unroll
        for (int r = 0; r < RDEC; ++r) {
            c1[r] = sigm(a[r].y) * c1[r] + sigm(a[r].x) * ftanh(a[r].z);
            h1h[(j >> 1) * 32 + r * 2 + (j & 1)] = (_Float16)(sigm(a[r].w) * ftanh(c1[r]));
        }
        __syncthreads();
        // ---- mu / sigma / sample ----
        int wave = j >> 6, lane = j & 63;
        for (int r = wave; r < RDEC; r += 4) {
            float sm = 0.0f, ss = 0.0f;
            #pragma unroll
            for (int q = 0; q < 4; ++q) {
                int k = lane + 64 * q;
                float hv = (float)h1h[(k >> 1) * 32 + r * 2 + (k & 1)];
                sm = fmaf(w_mu[k], hv, sm);
                ss = fmaf(w_sigma[k], hv, ss);
            }
            #pragma unroll
            for (int off = 32; off > 0; off >>= 1) {
                sm += __shfl_down(sm, off, 64);
                ss += __shfl_down(ss, off, 64);
            }
            if (lane == 0) {
                float mu = sm + b_mu[0];
                float sg = softplus(ss + b_sigma[0]);
                int gr = gr0 + r;
                float smp = fmaf(sg, eps[st * GROWS + gr], mu);
                atomicAdd(&acc[(gr / NS) * PRED + st], smp);
                #pragma unroll
                for (int f = 0; f < NLAG - 1; ++f) bufs[r][f] = bufs[r][f + 1];
                bufs[r][NLAG - 1] = smp;
            }
        }
        __syncthreads();
    }
}

// ---------------- kernel 5: finalize ----------------
__global__ __launch_bounds__(256) void finalize_kernel(const float* __restrict__ ws,
                                                       float* __restrict__ out) {
    int i = blockIdx.x * blockDim.x + threadIdx.x;
    if (i < BATCH * PRED) {
        int b = i / PRED;
        out[i] = ws[OFF_ACC + i] * (1.0f / NS) * ws[OFF_SCALE + b] + ws[OFF_LOC + b];
    }
}

// ---------------- launch ----------------
extern "C" void kernel_launch(void* const* d_in, const int* in_sizes, int n_in,
                              void* d_out, int out_size, void* d_ws, size_t ws_size,
                              hipStream_t stream) {
    const float* targets = (const float*)d_in[0];
    const float* w_ih0 = (const float*)d_in[1];
    const float* w_hh0 = (const float*)d_in[2];
    const float* b_ih0 = (const float*)d_in[3];
    const float* b_hh0 = (const float*)d_in[4];
    const float* w_ih1 = (const float*)d_in[5];
    const float* w_hh1 = (const float*)d_in[6];
    const float* b_ih1 = (const float*)d_in[7];
    const float* b_hh1 = (const float*)d_in[8];
    const float* w_mu = (const float*)d_in[9];
    const float* b_mu = (const float*)d_in[10];
    const float* w_sigma = (const float*)d_in[11];
    const float* b_sigma = (const float*)d_in[12];
    const float* eps = (const float*)d_in[13];
    float* ws = (float*)d_ws;
    float* out = (float*)d_out;

    hipLaunchKernelGGL(prep_weights, dim3(1024), dim3(256), 0, stream,
                       w_ih0, w_hh0, b_ih0, b_hh0, w_ih1, w_hh1, b_ih1, b_hh1, ws);
    hipLaunchKernelGGL(prep_norm, dim3(BATCH), dim3(256), 0, stream, targets, ws);
    hipLaunchKernelGGL(encoder_kernel, dim3(BATCH / 2), dim3(256), 0, stream, ws, ws);
    hipLaunchKernelGGL(decoder_kernel, dim3(GROWS / RDEC), dim3(256), 0, stream,
                       ws, w_mu, b_mu, w_sigma, b_sigma, eps, ws);
    hipLaunchKernelGGL(finalize_kernel, dim3((BATCH * PRED + 255) / 256), dim3(256), 0,
                       stream, ws, out);
}